// Round 6
// baseline (334.963 us; speedup 1.0000x reference)
//
#include <hip/hip_runtime.h>
#include <cstdint>

// Problem dims
#define Bdim 8192   // batch
#define Hdim 1024   // hidden units (per gate)
#define Kdim 2048   // IN + H
// Tile dims
#define BM 128      // rows per block
#define BU 64       // units per block (x4 gates = 256 effective N)
#define NSLAB (Kdim / 32)   // 64 slabs of 32 k

#define ASZ (BM * 32)       // elems per A slab buffer (8 KB)
#define BSZ (4 * BU * 32)   // elems per B slab buffer (16 KB)

#define XELEMS ((size_t)Bdim * Kdim)        // 16,777,216
#define WELEMS ((size_t)4 * Hdim * Kdim)    //  8,388,608
#define WGATE  ((size_t)Hdim * Kdim)        //  2,097,152

typedef __bf16 bf16;
typedef bf16  bf16x8   __attribute__((ext_vector_type(8)));
typedef float floatx16 __attribute__((ext_vector_type(16)));

typedef __attribute__((address_space(1))) uint32_t gu32;
typedef __attribute__((address_space(3))) uint32_t lu32;

__device__ __forceinline__ void gl_lds16(const bf16* g, bf16* l) {
    __builtin_amdgcn_global_load_lds((gu32*)(bf16*)g, (lu32*)l, 16, 0, 0);
}

__device__ __forceinline__ float sigf(float x) {
    return 1.0f / (1.0f + __expf(-x));
}
__device__ __forceinline__ float tanhfast(float x) {
    return 2.0f / (1.0f + __expf(-2.0f * x)) - 1.0f;
}

// bank swizzle: global k-chunk q of LDS row r stored at slot q ^ fsw(r).
// fsw(r)^fsw(r+2) always has bit1 set -> no collision in {4a..4a+3, 32+4a..}
// quarter-pair phases; same-parity rows within 8 take 4 distinct slots.
__device__ __forceinline__ int fsw(int r) {
    return (((r >> 1) & 1) << 1) | ((r >> 2) & 1);
}

// ---------------- fp32 -> bf16 conversion pre-pass ----------------
__global__ __launch_bounds__(256) void cvt_kernel(
    const float* __restrict__ inp, const float* __restrict__ hid,
    const float* __restrict__ Wf,  const float* __restrict__ Wi,
    const float* __restrict__ Wo,  const float* __restrict__ Wc,
    bf16* __restrict__ xc, bf16* __restrict__ wc)
{
    const size_t id = (size_t)blockIdx.x * 256 + threadIdx.x;  // 8-elem chunk
    const size_t e  = id * 8;
    const float* src;
    bf16* dst;
    if (e < XELEMS) {
        const size_t b = e >> 11;          // row (K=2048)
        const size_t k = e & (Kdim - 1);
        src = (k < Hdim) ? (hid + b * Hdim + k) : (inp + b * Hdim + (k - Hdim));
        dst = xc + e;
    } else {
        const size_t w = e - XELEMS;
        const size_t g = w >> 21;          // 2^21 == H*K
        const float* Ws = (g == 0) ? Wf : (g == 1) ? Wi : (g == 2) ? Wo : Wc;
        src = Ws + (w & (WGATE - 1));
        dst = wc + w;
    }
    const float4 a  = *reinterpret_cast<const float4*>(src);
    const float4 b4 = *reinterpret_cast<const float4*>(src + 4);
    bf16x8 o;
    o[0] = (bf16)a.x;  o[1] = (bf16)a.y;  o[2] = (bf16)a.z;  o[3] = (bf16)a.w;
    o[4] = (bf16)b4.x; o[5] = (bf16)b4.y; o[6] = (bf16)b4.z; o[7] = (bf16)b4.w;
    *reinterpret_cast<bf16x8*>(dst) = o;
}

// ---------------- fused LSTM GEMM + epilogue ----------------
// 32x32x16 MFMA, wave tile 64 rows x 32 units x 4 gates.
// Double-buffered 32-k slabs with raw vmcnt(6)/s_barrier pipeline:
// slab s+2 is staged into the buffer slab s just vacated; at each slab top we
// wait only for the oldest 6 DMA loads, keeping the prefetch in flight.
__global__ __launch_bounds__(256, 2) void lstm_fused(
    const bf16* __restrict__ xc,   const bf16* __restrict__ wc,
    const float* __restrict__ cin,
    const float* __restrict__ bfv, const float* __restrict__ biv,
    const float* __restrict__ bov, const float* __restrict__ bcv,
    float* __restrict__ out)
{
    __shared__ __align__(16) bf16 As[2 * ASZ];   // 16 KB
    __shared__ __align__(16) bf16 Bs[2 * BSZ];   // 32 KB

    const int tid  = threadIdx.x;
    const int lane = tid & 63;
    const int wv   = tid >> 6;
    const int m31  = lane & 31;
    const int h32  = lane >> 5;

    const int m0 = blockIdx.x * BM;
    const int u0 = blockIdx.y * BU;

    // ---- staging setup (source-side swizzle; LDS dest = base + lane*16) ----
    const bf16* gA[2];
    bf16* lA[2];
    #pragma unroll
    for (int c = 0; c < 2; ++c) {
        const int li   = c * 256 + tid;
        const int row  = li >> 2;
        const int slot = li & 3;
        const int gch  = slot ^ fsw(row);
        gA[c] = xc + (size_t)(m0 + row) * Kdim + gch * 8;
        lA[c] = &As[li * 8];
    }
    const bf16* gB[4];
    bf16* lB[4];
    #pragma unroll
    for (int c = 0; c < 4; ++c) {
        const int li   = c * 256 + tid;
        const int nr   = li >> 2;
        const int slot = li & 3;
        const int gch  = slot ^ fsw(nr);
        const int g    = nr >> 6;
        const int ul   = nr & 63;
        gB[c] = wc + (size_t)g * WGATE + (size_t)(u0 + ul) * Kdim + gch * 8;
        lB[c] = &Bs[li * 8];
    }

    // ---- fragment read offsets (elements) ----
    const int rbase = (wv & 1) * 64;
    const int ubase = (wv >> 1) * 32;
    int aoff[2][2];                     // [a: row frag][ks: k-half]
    #pragma unroll
    for (int a = 0; a < 2; ++a) {
        const int ra = rbase + a * 32 + m31;
        #pragma unroll
        for (int ks = 0; ks < 2; ++ks)
            aoff[a][ks] = ra * 32 + (((ks * 2 + h32) ^ fsw(ra)) * 8);
    }
    int boff[4][2];                     // [g: gate][ks]
    #pragma unroll
    for (int g = 0; g < 4; ++g) {
        const int rb = g * 64 + ubase + m31;
        #pragma unroll
        for (int ks = 0; ks < 2; ++ks)
            boff[g][ks] = rb * 32 + (((ks * 2 + h32) ^ fsw(rb)) * 8);
    }

    floatx16 acc[2][4] = {};            // [a: row frag][g: gate]

    // ---- prologue: stage slabs 0,1 into bufs 0,1 (12 loads in flight) ----
    #pragma unroll
    for (int s = 0; s < 2; ++s) {
        const int kk = s * 32;
        gl_lds16(gA[0] + kk, lA[0] + s * ASZ);
        gl_lds16(gA[1] + kk, lA[1] + s * ASZ);
        gl_lds16(gB[0] + kk, lB[0] + s * BSZ);
        gl_lds16(gB[1] + kk, lB[1] + s * BSZ);
        gl_lds16(gB[2] + kk, lB[2] + s * BSZ);
        gl_lds16(gB[3] + kk, lB[3] + s * BSZ);
    }

    for (int s = 0; s < NSLAB; ++s) {
        // wait for this slab's 6 loads only (prefetch stays in flight)
        if (s == NSLAB - 1) __builtin_amdgcn_s_waitcnt(0xF70);  // vmcnt(0)
        else                __builtin_amdgcn_s_waitcnt(0xF76);  // vmcnt(6)
        __builtin_amdgcn_s_barrier();

        const int sel = s & 1;
        const bf16* Ab = As + sel * ASZ;
        const bf16* Bb = Bs + sel * BSZ;
        bf16x8 af[2][2];
        #pragma unroll
        for (int a = 0; a < 2; ++a)
            #pragma unroll
            for (int ks = 0; ks < 2; ++ks)
                af[a][ks] = *reinterpret_cast<const bf16x8*>(Ab + aoff[a][ks]);
        bf16x8 bg[4][2];
        #pragma unroll
        for (int g = 0; g < 4; ++g)
            #pragma unroll
            for (int ks = 0; ks < 2; ++ks)
                bg[g][ks] = *reinterpret_cast<const bf16x8*>(Bb + boff[g][ks]);

        #pragma unroll
        for (int ks = 0; ks < 2; ++ks)
            #pragma unroll
            for (int a = 0; a < 2; ++a)
                #pragma unroll
                for (int g = 0; g < 4; ++g)
                    acc[a][g] = __builtin_amdgcn_mfma_f32_32x32x16_bf16(
                        af[a][ks], bg[g][ks], acc[a][g], 0, 0, 0);

        if (s + 2 < NSLAB) {
            // all waves consumed buf `sel` (MFMA deps force lgkm drain);
            // barrier, then refill it with slab s+2
            __builtin_amdgcn_s_barrier();
            const int kk = (s + 2) * 32;
            gl_lds16(gA[0] + kk, lA[0] + sel * ASZ);
            gl_lds16(gA[1] + kk, lA[1] + sel * ASZ);
            gl_lds16(gB[0] + kk, lB[0] + sel * BSZ);
            gl_lds16(gB[1] + kk, lB[1] + sel * BSZ);
            gl_lds16(gB[2] + kk, lB[2] + sel * BSZ);
            gl_lds16(gB[3] + kk, lB[3] + sel * BSZ);
        }
    }

    // ---- fused LSTM epilogue (one unit per lane) ----
    const int m_base = m0 + rbase + 4 * h32;
    const int unit   = u0 + ubase + m31;
    const float bff = bfv[unit];
    const float bii = biv[unit];
    const float boo = bov[unit];
    const float bcc = bcv[unit];
    #pragma unroll
    for (int a = 0; a < 2; ++a) {
        #pragma unroll
        for (int rg = 0; rg < 16; ++rg) {
            const int row = m_base + a * 32 + (rg & 3) + 8 * (rg >> 2);
            const size_t off = (size_t)row * Hdim + unit;
            const float fg = sigf(acc[a][0][rg] + bff);
            const float ig = sigf(acc[a][1][rg] + bii);
            const float og = sigf(acc[a][2][rg] + boo);
            const float ch = tanhfast(acc[a][3][rg] + bcc);
            const float cn = fg * cin[off] + ig * ch;
            const float hn = og * tanhfast(cn);
            out[off] = hn;                         // h_new
            out[(size_t)Bdim * Hdim + off] = cn;   // c_new
        }
    }
}

extern "C" void kernel_launch(void* const* d_in, const int* in_sizes, int n_in,
                              void* d_out, int out_size, void* d_ws, size_t ws_size,
                              hipStream_t stream) {
    const float* inputs = (const float*)d_in[0];
    const float* hidden = (const float*)d_in[1];
    const float* cprev  = (const float*)d_in[2];
    const float* Wf     = (const float*)d_in[3];
    const float* bfp    = (const float*)d_in[4];
    const float* Wi     = (const float*)d_in[5];
    const float* bip    = (const float*)d_in[6];
    const float* Wo     = (const float*)d_in[7];
    const float* bop    = (const float*)d_in[8];
    const float* Wc     = (const float*)d_in[9];
    const float* bcp    = (const float*)d_in[10];
    float* out = (float*)d_out;

    const size_t need = (XELEMS + WELEMS) * sizeof(bf16);
    if (ws_size < need) return;
    bf16* xc = (bf16*)d_ws;
    bf16* wc = xc + XELEMS;

    const int cvt_blocks = (int)((XELEMS + WELEMS) / 8 / 256);  // 12288
    cvt_kernel<<<dim3(cvt_blocks), dim3(256), 0, stream>>>(
        inputs, hidden, Wf, Wi, Wo, Wc, xc, wc);

    dim3 grid(Bdim / BM, Hdim / BU);   // 64 x 16 = 1024 blocks
    lstm_fused<<<grid, dim3(256), 0, stream>>>(
        xc, wc, cprev, bfp, bip, bop, bcp, out);
}